// Round 17
// baseline (1392.458 us; speedup 1.0000x reference)
//
#include <hip/hip_runtime.h>

#define BB 512
#define TT 2048
#define DD 8
#define HH 64
#define NB 4                // batch columns per block (1/4 of the MFMA N-tile)
#define NBLK (BB / NB)      // 128 blocks -> 128 CUs, no cross-CU traffic

typedef _Float16 f16x8 __attribute__((ext_vector_type(8)));
typedef __fp16   fp16x2 __attribute__((ext_vector_type(2)));
typedef float    f32x4 __attribute__((ext_vector_type(4)));

__device__ __forceinline__ float rcpf(float x) { return __builtin_amdgcn_rcpf(x); }
__device__ __forceinline__ float sigm(float x) { return rcpf(1.0f + __expf(-x)); }
__device__ __forceinline__ float tanh_fast(float x) {
  return 1.0f - 2.0f * rcpf(__expf(2.0f * x) + 1.0f);
}
__device__ __forceinline__ f16x8 cvt8(const float* __restrict__ p) {
  f16x8 r;
#pragma unroll
  for (int e = 0; e < 8; ++e) r[e] = (_Float16)p[e];
  return r;
}

// DS-only barrier (R15): LDS publishes retired, x-prefetch stays in flight.
#define DSBAR()                                          \
  do {                                                   \
    asm volatile("s_waitcnt lgkmcnt(0)" ::: "memory");   \
    __builtin_amdgcn_s_barrier();                        \
    __builtin_amdgcn_sched_barrier(0);                   \
  } while (0)

// R17: PHASE-SHIFTED TWO-BARRIER STEP.
// R16 counters (active-CU: VALUBusy 44% = 650cyc, MfmaUtil 32% = 464cyc of a
// 1460cyc step) show the two wave groups alternate bursts in lockstep: both
// do MFMA together (VALU idle), then both do act together (MFMA idle) -- the
// step is the SUM of bursts. Shift L1 half a step: with 2 barriers/iter,
//   phase1: L0 {read h0[t-1], 2-deep MFMA on xpre}  ||  L1 {act+publish h1[t-2]}
//   phase2: L0 {swizzle+act+publish h0[t], xpre[t+1]} || L1 {read, 4 MFMA}
// MFMA and act bursts now overlap on every SIMD. All handoffs cross exactly
// one barrier; parity buffers unchanged; per-value arithmetic identical
// (absmax must stay 2^-10). Barrier-only sync -- no flags, no spin risk.
__global__ void __launch_bounds__(512, 1)
lstm2_mfma(const float* __restrict__ x,
           const float* __restrict__ w_ih0, const float* __restrict__ w_hh0,
           const float* __restrict__ b_ih0, const float* __restrict__ b_hh0,
           const float* __restrict__ w_ih1, const float* __restrict__ w_hh1,
           const float* __restrict__ b_ih1, const float* __restrict__ b_hh1,
           const float* __restrict__ w_out, const float* __restrict__ b_out,
           float* __restrict__ out)
{
  const int tid  = threadIdx.x;
  const int lane = tid & 63;
  const int wq   = tid >> 6;    // wave 0..7
  const int lay  = wq >> 2;     // 0: layer-0 wave, 1: layer-1 wave
  const int q    = wq & 3;      // 16-row k-slice within the layer
  const int lg   = lane >> 4;   // k-group 0..3 (MFMA A/B/C row group)
  const int ar   = lane & 15;   // B-col / C-col (batch); only ar<4 valid
  const int col  = lane & 3;    // redistributed: batch col 0..3
  const int rsel = (lane >> 2) & 3;  // source register this lane takes
  const int tile = blockIdx.x;

  __shared__ __align__(16) unsigned char h0buf[2][16][128];  // fp16, parity dbuf
  __shared__ __align__(16) unsigned char h1buf[2][16][128];  // rows 4..15 stay 0
  __shared__ float hout[HH][NB];

  {  // zero both h buffers (h[-1],h[-2]=0; rows 4..15 must stay 0 forever)
    float* z0 = (float*)h0buf;
    float* z1 = (float*)h1buf;
    for (int i = tid; i < (int)(sizeof(h0buf) / 4); i += 512) { z0[i] = 0.f; z1[i] = 0.f; }
  }

  // ---- static A-fragments (this wave's layer only) + bias C-registers ----
  f16x8 a_x[4];        // L0 only: w_ih0 (k=0..7 live)
  f16x8 aU[4][2];      // L0: w_hh0   |   L1: w_ih1
  f16x8 aV[4][2];      // L1: w_hh1
  f32x4 bC[4];
#pragma unroll
  for (int ti = 0; ti < 4; ++ti) {
    const int tile_m = q + 4 * ti;      // ti: 0=i 1=f 2=g 3=o
    const int ga     = 16 * tile_m + ar;
    f16x8 zf = {};
    a_x[ti] = zf;
    if (lay == 0) {
      if (lg == 0) a_x[ti] = cvt8(w_ih0 + ga * DD);
#pragma unroll
      for (int kf = 0; kf < 2; ++kf) {
        aU[ti][kf] = cvt8(w_hh0 + ga * HH + kf * 32 + lg * 8);
        aV[ti][kf] = zf;
      }
#pragma unroll
      for (int r = 0; r < 4; ++r) {
        const int gc = 16 * tile_m + 4 * lg + r;
        bC[ti][r] = b_ih0[gc] + b_hh0[gc];
      }
    } else {
#pragma unroll
      for (int kf = 0; kf < 2; ++kf) {
        const int off = ga * HH + kf * 32 + lg * 8;
        aU[ti][kf] = cvt8(w_ih1 + off);
        aV[ti][kf] = cvt8(w_hh1 + off);
      }
#pragma unroll
      for (int r = 0; r < 4; ++r) {
        const int gc = 16 * tile_m + 4 * lg + r;
        bC[ti][r] = b_ih1[gc] + b_hh1[gc];
      }
    }
  }

  // x stream (L0 waves; lanes ar>=4 read clamped row 0 of tile, unused)
  const int xr = tile * NB + (ar < NB ? ar : 0);
  const float4* xrow = (const float4*)(x + (size_t)xr * TT * DD);
  float4 xA = make_float4(0, 0, 0, 0), xB = make_float4(0, 0, 0, 0);
  if (lay == 0) { xA = xrow[0]; xB = xrow[1]; }

  float cv  = 0.0f;   // ONE c-update per lane
  float hv1 = 0.0f;   // L1: final h1 fp32 for the head

  // lane's (row,col) after swizzle: kk = 16q + 4*(lane>>4) + rsel, col = lane&3
  const int kk   = 16 * q + 4 * (lane >> 4) + rsel;
  const int pubB = 16 * ((kk >> 3) ^ col) + 2 * (kk & 7);
  const int rd0  = 16 * ((0 + lg) ^ (ar & 7));
  const int rd1  = 16 * ((4 + lg) ^ (ar & 7));

  // L0: xpre = bias0 + Wih0 @ x[t]  (precomputed one phase ahead)
  f32x4 xpre[4];
  if (lay == 0) {
    f16x8 xf = {};
    if (lg == 0 && ar < NB) {
      union { fp16x2 h2[4]; f16x8 v; } X;
      X.h2[0] = __builtin_amdgcn_cvt_pkrtz(xA.x, xA.y);
      X.h2[1] = __builtin_amdgcn_cvt_pkrtz(xA.z, xA.w);
      X.h2[2] = __builtin_amdgcn_cvt_pkrtz(xB.x, xB.y);
      X.h2[3] = __builtin_amdgcn_cvt_pkrtz(xB.z, xB.w);
      xf = X.v;
    }
#pragma unroll
    for (int ti = 0; ti < 4; ++ti)
      xpre[ti] = __builtin_amdgcn_mfma_f32_16x16x32_f16(a_x[ti], xf, bC[ti], 0, 0, 0);
  }

  f32x4 gatesR[4];   // L0: gates0(t) phase1->phase2 | L1: gates1 across iters
#pragma unroll
  for (int ti = 0; ti < 4; ++ti) gatesR[ti] = (f32x4){0.f, 0.f, 0.f, 0.f};

  __syncthreads();

  for (int t = 0; t <= TT; ++t) {
    const int p  = t & 1;
    const int rp = p ^ 1;

    // ================= phase 1 =================
    if (lay == 0) {
      // read h0[t-1], two chained MFMAs on top of xpre (= b + Wx[t])
      const f16x8 hf0_0 = *(const f16x8*)&h0buf[rp][ar][rd0];
      const f16x8 hf0_1 = *(const f16x8*)&h0buf[rp][ar][rd1];
#pragma unroll
      for (int ti = 0; ti < 4; ++ti)
        gatesR[ti] = __builtin_amdgcn_mfma_f32_16x16x32_f16(aU[ti][0], hf0_0, xpre[ti], 0, 0, 0);
#pragma unroll
      for (int ti = 0; ti < 4; ++ti)
        gatesR[ti] = __builtin_amdgcn_mfma_f32_16x16x32_f16(aU[ti][1], hf0_1, gatesR[ti], 0, 0, 0);
      {  // prefetch x[t+1] (consumed in phase2's xpre build)
        const int tn = (t + 1 < TT) ? (t + 1) : (TT - 1);
        xA = xrow[2 * tn];
        xB = xrow[2 * tn + 1];
      }
    } else if (t >= 2) {
      // act gates for h1[t-2] (computed iter t-1 phase2), publish to parity t&1
      f32x4 ga;
#pragma unroll
      for (int ti = 0; ti < 4; ++ti) {
        const int s0 = __builtin_amdgcn_ds_swizzle(__float_as_int(gatesR[ti][0]), 0x0013);
        const int s1 = __builtin_amdgcn_ds_swizzle(__float_as_int(gatesR[ti][1]), 0x0013);
        const int s2 = __builtin_amdgcn_ds_swizzle(__float_as_int(gatesR[ti][2]), 0x0013);
        const int s3 = __builtin_amdgcn_ds_swizzle(__float_as_int(gatesR[ti][3]), 0x0013);
        const int v01 = (rsel & 1) ? s1 : s0;
        const int v23 = (rsel & 1) ? s3 : s2;
        ga[ti] = __int_as_float((rsel & 2) ? v23 : v01);
      }
      const float i_ = sigm(ga[0]);
      const float f_ = sigm(ga[1]);
      const float g_ = tanh_fast(ga[2]);
      const float o_ = sigm(ga[3]);
      cv = fmaf(f_, cv, i_ * g_);
      hv1 = o_ * tanh_fast(cv);
      *(_Float16*)&h1buf[p][col][pubB] = (_Float16)hv1;
    }

    DSBAR();  // B1

    // ================= phase 2 =================
    if (lay == 0) {
      // swizzle+act+publish h0[t]
      f32x4 ga;
#pragma unroll
      for (int ti = 0; ti < 4; ++ti) {
        const int s0 = __builtin_amdgcn_ds_swizzle(__float_as_int(gatesR[ti][0]), 0x0013);
        const int s1 = __builtin_amdgcn_ds_swizzle(__float_as_int(gatesR[ti][1]), 0x0013);
        const int s2 = __builtin_amdgcn_ds_swizzle(__float_as_int(gatesR[ti][2]), 0x0013);
        const int s3 = __builtin_amdgcn_ds_swizzle(__float_as_int(gatesR[ti][3]), 0x0013);
        const int v01 = (rsel & 1) ? s1 : s0;
        const int v23 = (rsel & 1) ? s3 : s2;
        ga[ti] = __int_as_float((rsel & 2) ? v23 : v01);
      }
      const float i_ = sigm(ga[0]);
      const float f_ = sigm(ga[1]);
      const float g_ = tanh_fast(ga[2]);
      const float o_ = sigm(ga[3]);
      cv = fmaf(f_, cv, i_ * g_);
      const float h = o_ * tanh_fast(cv);
      *(_Float16*)&h0buf[p][col][pubB] = (_Float16)h;

      // xpre for step t+1 (independent of everything above; fills MFMA pipe)
      f16x8 xf = {};
      if (lg == 0 && ar < NB) {
        union { fp16x2 h2[4]; f16x8 v; } X;
        X.h2[0] = __builtin_amdgcn_cvt_pkrtz(xA.x, xA.y);
        X.h2[1] = __builtin_amdgcn_cvt_pkrtz(xA.z, xA.w);
        X.h2[2] = __builtin_amdgcn_cvt_pkrtz(xB.x, xB.y);
        X.h2[3] = __builtin_amdgcn_cvt_pkrtz(xB.z, xB.w);
        xf = X.v;
      }
#pragma unroll
      for (int ti = 0; ti < 4; ++ti)
        xpre[ti] = __builtin_amdgcn_mfma_f32_16x16x32_f16(a_x[ti], xf, bC[ti], 0, 0, 0);
    } else {
      // read h0[t-1] (parity rp) and h1[t-2] (parity p, published in phase1);
      // 4 MFMAs -> gates for h1[t-1], acted next iter phase1
      const f16x8 hf0_0 = *(const f16x8*)&h0buf[rp][ar][rd0];
      const f16x8 hf0_1 = *(const f16x8*)&h0buf[rp][ar][rd1];
      const f16x8 hf1_0 = *(const f16x8*)&h1buf[p][ar][rd0];
      const f16x8 hf1_1 = *(const f16x8*)&h1buf[p][ar][rd1];
#pragma unroll
      for (int ti = 0; ti < 4; ++ti)
        gatesR[ti] = __builtin_amdgcn_mfma_f32_16x16x32_f16(aU[ti][0], hf0_0, bC[ti], 0, 0, 0);
#pragma unroll
      for (int ti = 0; ti < 4; ++ti)
        gatesR[ti] = __builtin_amdgcn_mfma_f32_16x16x32_f16(aU[ti][1], hf0_1, gatesR[ti], 0, 0, 0);
#pragma unroll
      for (int ti = 0; ti < 4; ++ti)
        gatesR[ti] = __builtin_amdgcn_mfma_f32_16x16x32_f16(aV[ti][0], hf1_0, gatesR[ti], 0, 0, 0);
#pragma unroll
      for (int ti = 0; ti < 4; ++ti)
        gatesR[ti] = __builtin_amdgcn_mfma_f32_16x16x32_f16(aV[ti][1], hf1_1, gatesR[ti], 0, 0, 0);
    }

    DSBAR();  // B2
  }

  // ---- epilogue: L1 acts the final gates (h1[TT-1]); no publish needed ----
  if (lay == 1) {
    f32x4 ga;
#pragma unroll
    for (int ti = 0; ti < 4; ++ti) {
      const int s0 = __builtin_amdgcn_ds_swizzle(__float_as_int(gatesR[ti][0]), 0x0013);
      const int s1 = __builtin_amdgcn_ds_swizzle(__float_as_int(gatesR[ti][1]), 0x0013);
      const int s2 = __builtin_amdgcn_ds_swizzle(__float_as_int(gatesR[ti][2]), 0x0013);
      const int s3 = __builtin_amdgcn_ds_swizzle(__float_as_int(gatesR[ti][3]), 0x0013);
      const int v01 = (rsel & 1) ? s1 : s0;
      const int v23 = (rsel & 1) ? s3 : s2;
      ga[ti] = __int_as_float((rsel & 2) ? v23 : v01);
    }
    const float i_ = sigm(ga[0]);
    const float f_ = sigm(ga[1]);
    const float g_ = tanh_fast(ga[2]);
    const float o_ = sigm(ga[3]);
    cv = fmaf(f_, cv, i_ * g_);
    hv1 = o_ * tanh_fast(cv);
    hout[kk][col] = hv1;
  }
  __syncthreads();

  // ---- head: out[b] = h1[T-1] . w_out + b_out ----
  if (tid < NB) {
    float v = b_out[0];
    for (int k = 0; k < HH; ++k) v = fmaf(hout[k][tid], w_out[k], v);
    out[tile * NB + tid] = v;
  }
}

extern "C" void kernel_launch(void* const* d_in, const int* in_sizes, int n_in,
                              void* d_out, int out_size, void* d_ws, size_t ws_size,
                              hipStream_t stream) {
  const float* x     = (const float*)d_in[0];
  const float* w_ih0 = (const float*)d_in[1];
  const float* w_hh0 = (const float*)d_in[2];
  const float* b_ih0 = (const float*)d_in[3];
  const float* b_hh0 = (const float*)d_in[4];
  const float* w_ih1 = (const float*)d_in[5];
  const float* w_hh1 = (const float*)d_in[6];
  const float* b_ih1 = (const float*)d_in[7];
  const float* b_hh1 = (const float*)d_in[8];
  const float* w_out = (const float*)d_in[9];
  const float* b_out = (const float*)d_in[10];
  float* out = (float*)d_out;

  lstm2_mfma<<<dim3(NBLK), dim3(512), 0, stream>>>(
      x, w_ih0, w_hh0, b_ih0, b_hh0,
      w_ih1, w_hh1, b_ih1, b_hh1,
      w_out, b_out, out);
}